// Round 3
// baseline (610.558 us; speedup 1.0000x reference)
//
#include <hip/hip_runtime.h>
#include <math.h>
#include <stdint.h>

#define LN_EPS 1e-5f

// ---------- wave-wide helpers (wave64) ----------
__device__ __forceinline__ float wsum64(float v) {
#pragma unroll
  for (int m = 1; m < 64; m <<= 1) v += __shfl_xor(v, m, 64);
  return v;
}
__device__ __forceinline__ float wmax64(float v) {
#pragma unroll
  for (int m = 1; m < 64; m <<= 1) v = fmaxf(v, __shfl_xor(v, m, 64));
  return v;
}

// ---------- CSR build ----------
__global__ void k_zero_int(int* __restrict__ p, int n) {
  int i = blockIdx.x * blockDim.x + threadIdx.x;
  if (i < n) p[i] = 0;
}

__global__ void k_count(const int* __restrict__ dst, int* __restrict__ deg, int E) {
  int i = blockIdx.x * blockDim.x + threadIdx.x;
  if (i < E) atomicAdd(&deg[dst[i]], 1);
}

// pass1: per-block (1024 items) sums
__global__ __launch_bounds__(256) void k_scan1(const int* __restrict__ deg,
                                               int* __restrict__ bsum, int N) {
  __shared__ int sm[4];
  int t = threadIdx.x;
  int base = blockIdx.x * 1024 + t * 4;
  int s = 0;
#pragma unroll
  for (int i = 0; i < 4; ++i) { int idx = base + i; if (idx < N) s += deg[idx]; }
#pragma unroll
  for (int m = 1; m < 64; m <<= 1) s += __shfl_xor(s, m, 64);
  if ((t & 63) == 0) sm[t >> 6] = s;
  __syncthreads();
  if (t == 0) bsum[blockIdx.x] = sm[0] + sm[1] + sm[2] + sm[3];
}

// pass2: serial exclusive scan of ~98 block sums (trivial)
__global__ void k_scan2(const int* __restrict__ bsum, int* __restrict__ boff, int NB) {
  if (blockIdx.x == 0 && threadIdx.x == 0) {
    int run = 0;
    for (int i = 0; i < NB; ++i) { boff[i] = run; run += bsum[i]; }
  }
}

// pass3: per-block exclusive scan -> global offsets
__global__ __launch_bounds__(256) void k_scan3(const int* __restrict__ deg,
                                               const int* __restrict__ boff,
                                               int* __restrict__ offsets, int N) {
  __shared__ int ts[256];
  int t = threadIdx.x;
  int base = blockIdx.x * 1024 + t * 4;
  int v[4]; int s = 0;
#pragma unroll
  for (int i = 0; i < 4; ++i) { int idx = base + i; v[i] = (idx < N) ? deg[idx] : 0; s += v[i]; }
  ts[t] = s;
  __syncthreads();
  for (int off = 1; off < 256; off <<= 1) {   // Hillis-Steele inclusive scan
    int x = (t >= off) ? ts[t - off] : 0;
    __syncthreads();
    ts[t] += x;
    __syncthreads();
  }
  int run = ts[t] - s + boff[blockIdx.x];     // exclusive prefix for this thread
#pragma unroll
  for (int i = 0; i < 4; ++i) { int idx = base + i; if (idx < N) offsets[idx] = run; run += v[i]; }
}

// dinv = deg>0 ? rsqrt(deg) : 0 ; cursor = offsets copy ; offsets[N] = E
__global__ void k_dinv(const int* __restrict__ deg, int* __restrict__ offsets,
                       float* __restrict__ dinv, int* __restrict__ cursor, int N, int E) {
  int i = blockIdx.x * blockDim.x + threadIdx.x;
  if (i < N) {
    int d = deg[i];
    dinv[i] = d > 0 ? rsqrtf((float)d) : 0.f;
    cursor[i] = offsets[i];
  }
  if (i == 0) offsets[N] = E;
}

__global__ void k_place(const int* __restrict__ src, const int* __restrict__ dst,
                        int* __restrict__ cursor, int* __restrict__ csr, int E) {
  int i = blockIdx.x * blockDim.x + threadIdx.x;
  if (i < E) {
    int pos = atomicAdd(&cursor[dst[i]], 1);
    csr[pos] = src[i];
  }
}

// ---------- GEMM: out[m] = dinv[m] * (A[m] @ W), A:[M][K], W:[K][64] ----------
template <int K>
__global__ __launch_bounds__(256) void gemm_scale(const float* __restrict__ A,
                                                  const float* __restrict__ W,
                                                  const float* __restrict__ dinv,
                                                  float* __restrict__ out, int M) {
  __shared__ float xs[16][64];   // transposed A tile: xs[k][m]
  __shared__ float wsh[16][64];  // W tile: wsh[k][c]
  int t = threadIdx.x;
  int m0 = blockIdx.x * 64;
  int lm = t >> 2;              // 0..63: local row to load
  int lk = (t & 3) << 2;        // 0,4,8,12: k offset within chunk
  int mr = (t & 15) << 2;       // compute: 4 rows
  int cc = (t >> 4) << 2;       // compute: 4 cols
  float acc[4][4] = {{0.f}};
  int gm = m0 + lm;
  const bool mok = gm < M;
  for (int kc = 0; kc < K; kc += 16) {
    float4 av = make_float4(0.f, 0.f, 0.f, 0.f);
    if (mok) av = *(const float4*)&A[(size_t)gm * K + kc + lk];
    float wv[4];
#pragma unroll
    for (int r = 0; r < 4; ++r) {
      int k = (t >> 6) + (r << 2);
      wv[r] = W[(size_t)(kc + k) * 64 + (t & 63)];
    }
    __syncthreads();  // previous chunk's compute reads done
    xs[lk + 0][lm] = av.x;
    xs[lk + 1][lm] = av.y;
    xs[lk + 2][lm] = av.z;
    xs[lk + 3][lm] = av.w;
#pragma unroll
    for (int r = 0; r < 4; ++r) {
      int k = (t >> 6) + (r << 2);
      wsh[k][t & 63] = wv[r];
    }
    __syncthreads();
#pragma unroll
    for (int k = 0; k < 16; ++k) {
      float4 a4 = *(const float4*)&xs[k][mr];
      float4 b4 = *(const float4*)&wsh[k][cc];
      float a[4] = {a4.x, a4.y, a4.z, a4.w};
      float b[4] = {b4.x, b4.y, b4.z, b4.w};
#pragma unroll
      for (int i = 0; i < 4; ++i)
#pragma unroll
        for (int j = 0; j < 4; ++j) acc[i][j] = fmaf(a[i], b[j], acc[i][j]);
    }
  }
#pragma unroll
  for (int i = 0; i < 4; ++i) {
    int row = m0 + mr + i;
    if (row < M) {
      float sc = dinv[row];
      float4 o = make_float4(acc[i][0] * sc, acc[i][1] * sc, acc[i][2] * sc, acc[i][3] * sc);
      *(float4*)&out[(size_t)row * 64 + cc] = o;
    }
  }
}

// ---------- aggregation + bias + LayerNorm + ReLU (wave per node, lane = feature) ----------
__global__ __launch_bounds__(256) void k_agg(const float* __restrict__ hs,
                                             const int* __restrict__ offsets,
                                             const int* __restrict__ csr,
                                             const float* __restrict__ dinv,
                                             const float* __restrict__ b,
                                             const float* __restrict__ g,
                                             const float* __restrict__ tt,
                                             float* __restrict__ out, int n) {
  int lane = threadIdx.x & 63;
  int node = blockIdx.x * 4 + (threadIdx.x >> 6);
  if (node >= n) return;
  int beg = offsets[node];
  int end = offsets[node + 1];
  float acc = 0.f;
  int e = beg;
  for (; e + 4 <= end; e += 4) {  // 4-wide unroll: independent gathers in flight
    int s0 = csr[e], s1 = csr[e + 1], s2 = csr[e + 2], s3 = csr[e + 3];
    float v0 = hs[(size_t)s0 * 64 + lane];
    float v1 = hs[(size_t)s1 * 64 + lane];
    float v2 = hs[(size_t)s2 * 64 + lane];
    float v3 = hs[(size_t)s3 * 64 + lane];
    acc += v0 + v1 + v2 + v3;
  }
  for (; e < end; ++e) acc += hs[(size_t)csr[e] * 64 + lane];
  float val = fmaf(acc, dinv[node], b[lane]);
  float mu = wsum64(val) * 0.015625f;      // /64
  float d = val - mu;
  float var = wsum64(d * d) * 0.015625f;
  float y = fmaf(g[lane] * d, rsqrtf(var + LN_EPS), tt[lane]);
  out[(size_t)node * 64 + lane] = fmaxf(y, 0.f);
}

// ---------- final: logits = h @ Wf + bf ; log_softmax (wave per node) ----------
__global__ __launch_bounds__(256) void k_final(const float* __restrict__ h,
                                               const float* __restrict__ Wf,
                                               const float* __restrict__ bf,
                                               float* __restrict__ out, int n) {
  __shared__ float Wl[64 * 40];
  __shared__ float bl[40];
  int t = threadIdx.x;
  for (int i = t; i < 64 * 40; i += 256) Wl[i] = Wf[i];
  if (t < 40) bl[t] = bf[t];
  __syncthreads();
  int lane = t & 63;
  int node = blockIdx.x * 4 + (t >> 6);
  if (node >= n) return;
  float hval = h[(size_t)node * 64 + lane];
  int c = lane < 40 ? lane : 0;
  float acc = bl[c];
#pragma unroll
  for (int k = 0; k < 64; ++k) {
    float hk = __shfl(hval, k, 64);   // broadcast h[k] from lane k
    acc = fmaf(hk, Wl[k * 40 + c], acc);
  }
  float logit = acc;
  float mv = (lane < 40) ? logit : -INFINITY;
  mv = wmax64(mv);
  float ex = (lane < 40) ? expf(logit - mv) : 0.f;
  float s = wsum64(ex);
  if (lane < 40) out[(size_t)node * 40 + lane] = logit - mv - logf(s);
}

// ---------- launch ----------
extern "C" void kernel_launch(void* const* d_in, const int* in_sizes, int n_in,
                              void* d_out, int out_size, void* d_ws, size_t ws_size,
                              hipStream_t stream) {
  const float* x  = (const float*)d_in[0];
  const int*   ei = (const int*)d_in[1];
  const float* W1 = (const float*)d_in[2];
  const float* b1 = (const float*)d_in[3];
  const float* g1 = (const float*)d_in[4];
  const float* t1 = (const float*)d_in[5];
  const float* W2 = (const float*)d_in[6];
  const float* b2 = (const float*)d_in[7];
  const float* g2 = (const float*)d_in[8];
  const float* t2 = (const float*)d_in[9];
  const float* W3 = (const float*)d_in[10];
  const float* b3 = (const float*)d_in[11];
  const float* g3 = (const float*)d_in[12];
  const float* t3 = (const float*)d_in[13];
  const float* Wf = (const float*)d_in[14];
  const float* bf = (const float*)d_in[15];
  float* out = (float*)d_out;

  const int N = in_sizes[0] / 128;
  const int E = in_sizes[1] / 2;
  const int* src = ei;
  const int* dst = ei + E;

  // workspace carve (256B-aligned regions)
  char* p = (char*)d_ws;
  auto carve = [&](size_t bytes) -> char* {
    char* r = p;
    p += (bytes + 255) & ~(size_t)255;
    return r;
  };
  const int NB = (N + 1023) / 1024;
  int*   deg     = (int*)carve((size_t)N * 4);
  int*   offsets = (int*)carve((size_t)(N + 1) * 4);
  int*   cursor  = (int*)carve((size_t)N * 4);
  int*   bsum    = (int*)carve((size_t)NB * 4);
  int*   boff    = (int*)carve((size_t)NB * 4);
  int*   csr     = (int*)carve((size_t)E * 4);
  float* dinv    = (float*)carve((size_t)N * 4);
  float* hs      = (float*)carve((size_t)N * 64 * 4);
  float* hA      = (float*)carve((size_t)N * 64 * 4);
  float* hB      = (float*)carve((size_t)N * 64 * 4);
  (void)ws_size; (void)n_in; (void)out_size;

  dim3 B(256);
  // CSR build
  k_zero_int<<<dim3((N + 255) / 256), B, 0, stream>>>(deg, N);
  k_count<<<dim3((E + 255) / 256), B, 0, stream>>>(dst, deg, E);
  k_scan1<<<dim3(NB), B, 0, stream>>>(deg, bsum, N);
  k_scan2<<<dim3(1), dim3(64), 0, stream>>>(bsum, boff, NB);
  k_scan3<<<dim3(NB), B, 0, stream>>>(deg, boff, offsets, N);
  k_dinv<<<dim3((N + 255) / 256), B, 0, stream>>>(deg, offsets, dinv, cursor, N, E);
  k_place<<<dim3((E + 255) / 256), B, 0, stream>>>(src, dst, cursor, csr, E);

  const int GB = (N + 63) / 64;
  const int GA = (N + 3) / 4;
  // layer 1
  gemm_scale<128><<<dim3(GB), B, 0, stream>>>(x, W1, dinv, hs, N);
  k_agg<<<dim3(GA), B, 0, stream>>>(hs, offsets, csr, dinv, b1, g1, t1, hA, N);
  // layer 2
  gemm_scale<64><<<dim3(GB), B, 0, stream>>>(hA, W2, dinv, hs, N);
  k_agg<<<dim3(GA), B, 0, stream>>>(hs, offsets, csr, dinv, b2, g2, t2, hB, N);
  // layer 3
  gemm_scale<64><<<dim3(GB), B, 0, stream>>>(hB, W3, dinv, hs, N);
  k_agg<<<dim3(GA), B, 0, stream>>>(hs, offsets, csr, dinv, b3, g3, t3, hA, N);
  // final projection + log_softmax
  k_final<<<dim3(GA), B, 0, stream>>>(hA, Wf, bf, out, N);
}

// Round 4
// 448.402 us; speedup vs baseline: 1.3616x; 1.3616x over previous
//
#include <hip/hip_runtime.h>
#include <math.h>
#include <stdint.h>

#define LN_EPS 1e-5f
#define GRP_SHIFT 7           // 128 nodes per bucket
#define MAXBUK 1024           // N <= 131072
#define PCHUNK 8192           // edges per partition block

// ---------- wave-wide helpers (wave64) ----------
__device__ __forceinline__ float wsum64(float v) {
#pragma unroll
  for (int m = 1; m < 64; m <<= 1) v += __shfl_xor(v, m, 64);
  return v;
}
__device__ __forceinline__ float wmax64(float v) {
#pragma unroll
  for (int m = 1; m < 64; m <<= 1) v = fmaxf(v, __shfl_xor(v, m, 64));
  return v;
}

// ---------- bf16 helpers (RNE) ----------
__device__ __forceinline__ unsigned short f2bf(float f) {
  unsigned int u = __float_as_uint(f);
  unsigned int r = u + 0x7fffu + ((u >> 16) & 1u);
  return (unsigned short)(r >> 16);
}
__device__ __forceinline__ float bf2f(unsigned short h) {
  return __uint_as_float(((unsigned int)h) << 16);
}

// ---------- CSR build, bucketed ----------
// 1) per-bucket edge counts (LDS histogram, aggregated global atomics)
__global__ __launch_bounds__(256) void k_bucket_count(const int* __restrict__ dst,
                                                      int* __restrict__ bcnt, int E, int NB) {
  __shared__ int hist[MAXBUK];
  int t = threadIdx.x;
  for (int i = t; i < NB; i += 256) hist[i] = 0;
  __syncthreads();
  int e0 = blockIdx.x * PCHUNK;
  int e1 = min(e0 + PCHUNK, E);
  for (int i = e0 + t; i < e1; i += 256) atomicAdd(&hist[dst[i] >> GRP_SHIFT], 1);
  __syncthreads();
  for (int i = t; i < NB; i += 256)
    if (hist[i]) atomicAdd(&bcnt[i], hist[i]);
}

// 2) exclusive scan of bucket counts -> bases + cursors (single block)
__global__ __launch_bounds__(256) void k_bucket_scan(const int* __restrict__ cnt,
                                                     int* __restrict__ base,
                                                     int* __restrict__ cur, int NB) {
  __shared__ int ts[256];
  int t = threadIdx.x;
  int v[4];
  int s = 0;
#pragma unroll
  for (int j = 0; j < 4; ++j) { int i = t * 4 + j; v[j] = (i < NB) ? cnt[i] : 0; s += v[j]; }
  ts[t] = s;
  __syncthreads();
  for (int o = 1; o < 256; o <<= 1) {
    int x = (t >= o) ? ts[t - o] : 0;
    __syncthreads();
    ts[t] += x;
    __syncthreads();
  }
  int run = ts[t] - s;
#pragma unroll
  for (int j = 0; j < 4; ++j) {
    int i = t * 4 + j;
    if (i < NB) { base[i] = run; cur[i] = run; }
    run += v[j];
  }
  if (t == 255) base[NB] = run;  // == E
}

// 3) partition edges into per-bucket regions ((src,dst) pairs, grouped writes)
__global__ __launch_bounds__(256) void k_partition(const int* __restrict__ src,
                                                   const int* __restrict__ dst,
                                                   int* __restrict__ bcur,
                                                   int2* __restrict__ pairs, int E, int NB) {
  __shared__ int hist[MAXBUK];
  __shared__ int base[MAXBUK];
  int t = threadIdx.x;
  for (int i = t; i < NB; i += 256) hist[i] = 0;
  __syncthreads();
  int e0 = blockIdx.x * PCHUNK;
  int e1 = min(e0 + PCHUNK, E);
  for (int i = e0 + t; i < e1; i += 256) atomicAdd(&hist[dst[i] >> GRP_SHIFT], 1);
  __syncthreads();
  for (int i = t; i < NB; i += 256) {
    int c = hist[i];
    base[i] = c ? atomicAdd(&bcur[i], c) : 0;
    hist[i] = 0;
  }
  __syncthreads();
  for (int i = e0 + t; i < e1; i += 256) {
    int d = dst[i];
    int b = d >> GRP_SHIFT;
    int r = atomicAdd(&hist[b], 1);
    pairs[base[b] + r] = make_int2(src[i], d);
  }
}

// 4) per-bucket: per-node degree (LDS), local scan -> offsets/dinv, csr scatter (L2-local)
__global__ __launch_bounds__(256) void k_bucket_place(const int2* __restrict__ pairs,
                                                      const int* __restrict__ bbase,
                                                      int* __restrict__ offsets,
                                                      float* __restrict__ dinv,
                                                      int* __restrict__ csr, int N, int E) {
  __shared__ int cnt[128];
  __shared__ int sc[128];
  int t = threadIdx.x;
  int b = blockIdx.x;
  int node0 = b << GRP_SHIFT;
  if (t < 128) cnt[t] = 0;
  int beg = bbase[b], end = bbase[b + 1];
  if (b == 0 && t == 0) offsets[N] = E;
  __syncthreads();
  for (int i = beg + t; i < end; i += 256) atomicAdd(&cnt[pairs[i].y - node0], 1);
  __syncthreads();
  if (t < 128) sc[t] = cnt[t];
  __syncthreads();
  for (int o = 1; o < 128; o <<= 1) {
    int x = (t < 128 && t >= o) ? sc[t - o] : 0;
    __syncthreads();
    if (t < 128) sc[t] += x;
    __syncthreads();
  }
  if (t < 128) {
    int excl = sc[t] - cnt[t];
    int node = node0 + t;
    if (node < N) {
      offsets[node] = beg + excl;
      int d = cnt[t];
      dinv[node] = d > 0 ? rsqrtf((float)d) : 0.f;
    }
    sc[t] = beg + excl;  // becomes write cursor
  }
  __syncthreads();
  for (int i = beg + t; i < end; i += 256) {
    int2 e = pairs[i];
    int pos = atomicAdd(&sc[e.y - node0], 1);
    csr[pos] = e.x;
  }
}

// ---------- GEMM: out[m] = bf16( dinv[m] * (A[m] @ W) ), A:[M][K], W:[K][64] ----------
template <int K>
__global__ __launch_bounds__(256) void gemm_scale(const float* __restrict__ A,
                                                  const float* __restrict__ W,
                                                  const float* __restrict__ dinv,
                                                  unsigned short* __restrict__ out, int M) {
  __shared__ float xs[16][64];   // transposed A tile: xs[k][m]
  __shared__ float wsh[16][64];  // W tile: wsh[k][c]
  int t = threadIdx.x;
  int m0 = blockIdx.x * 64;
  int lm = t >> 2;              // 0..63: local row to load
  int lk = (t & 3) << 2;        // 0,4,8,12: k offset within chunk
  int mr = (t & 15) << 2;       // compute: 4 rows
  int cc = (t >> 4) << 2;       // compute: 4 cols
  float acc[4][4] = {{0.f}};
  int gm = m0 + lm;
  const bool mok = gm < M;
  for (int kc = 0; kc < K; kc += 16) {
    float4 av = make_float4(0.f, 0.f, 0.f, 0.f);
    if (mok) av = *(const float4*)&A[(size_t)gm * K + kc + lk];
    float wv[4];
#pragma unroll
    for (int r = 0; r < 4; ++r) {
      int k = (t >> 6) + (r << 2);
      wv[r] = W[(size_t)(kc + k) * 64 + (t & 63)];
    }
    __syncthreads();  // previous chunk's compute reads done
    xs[lk + 0][lm] = av.x;
    xs[lk + 1][lm] = av.y;
    xs[lk + 2][lm] = av.z;
    xs[lk + 3][lm] = av.w;
#pragma unroll
    for (int r = 0; r < 4; ++r) {
      int k = (t >> 6) + (r << 2);
      wsh[k][t & 63] = wv[r];
    }
    __syncthreads();
#pragma unroll
    for (int k = 0; k < 16; ++k) {
      float4 a4 = *(const float4*)&xs[k][mr];
      float4 b4 = *(const float4*)&wsh[k][cc];
      float a[4] = {a4.x, a4.y, a4.z, a4.w};
      float b[4] = {b4.x, b4.y, b4.z, b4.w};
#pragma unroll
      for (int i = 0; i < 4; ++i)
#pragma unroll
        for (int j = 0; j < 4; ++j) acc[i][j] = fmaf(a[i], b[j], acc[i][j]);
    }
  }
#pragma unroll
  for (int i = 0; i < 4; ++i) {
    int row = m0 + mr + i;
    if (row < M) {
      float sc = dinv[row];
      ushort4 o;
      o.x = f2bf(acc[i][0] * sc);
      o.y = f2bf(acc[i][1] * sc);
      o.z = f2bf(acc[i][2] * sc);
      o.w = f2bf(acc[i][3] * sc);
      *(ushort4*)&out[(size_t)row * 64 + cc] = o;
    }
  }
}

// ---------- aggregation + bias + LayerNorm + ReLU (wave per node, lane = feature) ----------
__global__ __launch_bounds__(256) void k_agg(const unsigned short* __restrict__ hs,
                                             const int* __restrict__ offsets,
                                             const int* __restrict__ csr,
                                             const float* __restrict__ dinv,
                                             const float* __restrict__ b,
                                             const float* __restrict__ g,
                                             const float* __restrict__ tt,
                                             float* __restrict__ out, int n) {
  int lane = threadIdx.x & 63;
  int node = blockIdx.x * 4 + (threadIdx.x >> 6);
  if (node >= n) return;
  int beg = offsets[node];
  int end = offsets[node + 1];
  float acc = 0.f;
  int e = beg;
  for (; e + 8 <= end; e += 8) {  // 8 independent gathers in flight
    int s[8];
#pragma unroll
    for (int j = 0; j < 8; ++j) s[j] = csr[e + j];
    float v[8];
#pragma unroll
    for (int j = 0; j < 8; ++j) v[j] = bf2f(hs[(size_t)s[j] * 64 + lane]);
#pragma unroll
    for (int j = 0; j < 8; ++j) acc += v[j];
  }
  for (; e < end; ++e) acc += bf2f(hs[(size_t)csr[e] * 64 + lane]);
  float val = fmaf(acc, dinv[node], b[lane]);
  float mu = wsum64(val) * 0.015625f;      // /64
  float d = val - mu;
  float var = wsum64(d * d) * 0.015625f;
  float y = fmaf(g[lane] * d, rsqrtf(var + LN_EPS), tt[lane]);
  out[(size_t)node * 64 + lane] = fmaxf(y, 0.f);
}

// ---------- final: logits = h @ Wf + bf ; log_softmax (wave per node) ----------
__global__ __launch_bounds__(256) void k_final(const float* __restrict__ h,
                                               const float* __restrict__ Wf,
                                               const float* __restrict__ bf,
                                               float* __restrict__ out, int n) {
  __shared__ float Wl[64 * 40];
  __shared__ float bl[40];
  int t = threadIdx.x;
  for (int i = t; i < 64 * 40; i += 256) Wl[i] = Wf[i];
  if (t < 40) bl[t] = bf[t];
  __syncthreads();
  int lane = t & 63;
  int node = blockIdx.x * 4 + (t >> 6);
  if (node >= n) return;
  float hval = h[(size_t)node * 64 + lane];
  int c = lane < 40 ? lane : 0;
  float acc = bl[c];
#pragma unroll
  for (int k = 0; k < 64; ++k) {
    float hk = __shfl(hval, k, 64);   // broadcast h[k] from lane k
    acc = fmaf(hk, Wl[k * 40 + c], acc);
  }
  float logit = acc;
  float mv = (lane < 40) ? logit : -INFINITY;
  mv = wmax64(mv);
  float ex = (lane < 40) ? expf(logit - mv) : 0.f;
  float s = wsum64(ex);
  if (lane < 40) out[(size_t)node * 40 + lane] = logit - mv - logf(s);
}

// ---------- launch ----------
extern "C" void kernel_launch(void* const* d_in, const int* in_sizes, int n_in,
                              void* d_out, int out_size, void* d_ws, size_t ws_size,
                              hipStream_t stream) {
  const float* x  = (const float*)d_in[0];
  const int*   ei = (const int*)d_in[1];
  const float* W1 = (const float*)d_in[2];
  const float* b1 = (const float*)d_in[3];
  const float* g1 = (const float*)d_in[4];
  const float* t1 = (const float*)d_in[5];
  const float* W2 = (const float*)d_in[6];
  const float* b2 = (const float*)d_in[7];
  const float* g2 = (const float*)d_in[8];
  const float* t2 = (const float*)d_in[9];
  const float* W3 = (const float*)d_in[10];
  const float* b3 = (const float*)d_in[11];
  const float* g3 = (const float*)d_in[12];
  const float* t3 = (const float*)d_in[13];
  const float* Wf = (const float*)d_in[14];
  const float* bf = (const float*)d_in[15];
  float* out = (float*)d_out;

  const int N = in_sizes[0] / 128;
  const int E = in_sizes[1] / 2;
  const int* src = ei;
  const int* dst = ei + E;
  const int NBUK = (N + 127) >> GRP_SHIFT;   // 782 for N=100000 (<= MAXBUK)
  const int NEB  = (E + PCHUNK - 1) / PCHUNK;

  // workspace carve (256B-aligned regions)
  char* p = (char*)d_ws;
  auto carve = [&](size_t bytes) -> char* {
    char* r = p;
    p += (bytes + 255) & ~(size_t)255;
    return r;
  };
  int*   bcnt    = (int*)carve((size_t)NBUK * 4);
  int*   bbase   = (int*)carve((size_t)(NBUK + 1) * 4);
  int*   bcur    = (int*)carve((size_t)NBUK * 4);
  int2*  pairs   = (int2*)carve((size_t)E * 8);
  int*   csr     = (int*)carve((size_t)E * 4);
  int*   offsets = (int*)carve((size_t)(N + 1) * 4);
  float* dinv    = (float*)carve((size_t)N * 4);
  unsigned short* hs = (unsigned short*)carve((size_t)N * 64 * 2);
  float* hA      = (float*)carve((size_t)N * 64 * 4);
  float* hB      = (float*)carve((size_t)N * 64 * 4);
  (void)ws_size; (void)n_in; (void)out_size;

  dim3 B(256);
  // CSR build (bucketed counting sort; no per-node global atomics)
  hipMemsetAsync(bcnt, 0, (size_t)NBUK * 4, stream);
  k_bucket_count<<<dim3(NEB), B, 0, stream>>>(dst, bcnt, E, NBUK);
  k_bucket_scan<<<dim3(1), B, 0, stream>>>(bcnt, bbase, bcur, NBUK);
  k_partition<<<dim3(NEB), B, 0, stream>>>(src, dst, bcur, pairs, E, NBUK);
  k_bucket_place<<<dim3(NBUK), B, 0, stream>>>(pairs, bbase, offsets, dinv, csr, N, E);

  const int GB = (N + 63) / 64;
  const int GA = (N + 3) / 4;
  // layer 1
  gemm_scale<128><<<dim3(GB), B, 0, stream>>>(x, W1, dinv, hs, N);
  k_agg<<<dim3(GA), B, 0, stream>>>(hs, offsets, csr, dinv, b1, g1, t1, hA, N);
  // layer 2
  gemm_scale<64><<<dim3(GB), B, 0, stream>>>(hA, W2, dinv, hs, N);
  k_agg<<<dim3(GA), B, 0, stream>>>(hs, offsets, csr, dinv, b2, g2, t2, hB, N);
  // layer 3
  gemm_scale<64><<<dim3(GB), B, 0, stream>>>(hB, W3, dinv, hs, N);
  k_agg<<<dim3(GA), B, 0, stream>>>(hs, offsets, csr, dinv, b3, g3, t3, hA, N);
  // final projection + log_softmax
  k_final<<<dim3(GA), B, 0, stream>>>(hA, Wf, bf, out, N);
}

// Round 5
// 365.751 us; speedup vs baseline: 1.6693x; 1.2260x over previous
//
#include <hip/hip_runtime.h>
#include <math.h>
#include <stdint.h>

#define LN_EPS 1e-5f
#define GRP_SHIFT 7           // 128 nodes per bucket
#define MAXBUK 1024           // N <= 131072
#define PCHUNK 8192           // edges per partition block

// ---------- wave helpers ----------
__device__ __forceinline__ float wsum32(float v) {   // reduce within each 32-lane half
#pragma unroll
  for (int m = 1; m < 32; m <<= 1) v += __shfl_xor(v, m, 64);
  return v;
}

// ---------- bf16 helpers (RNE) ----------
__device__ __forceinline__ unsigned short f2bf(float f) {
  unsigned int u = __float_as_uint(f);
  unsigned int r = u + 0x7fffu + ((u >> 16) & 1u);
  return (unsigned short)(r >> 16);
}
__device__ __forceinline__ float bfLo(unsigned v) { return __uint_as_float(v << 16); }
__device__ __forceinline__ float bfHi(unsigned v) { return __uint_as_float(v & 0xffff0000u); }

// ---------- CSR build, bucketed counting sort ----------
__global__ __launch_bounds__(256) void k_bucket_count(const int* __restrict__ dst,
                                                      int* __restrict__ bcnt, int E, int NB) {
  __shared__ int hist[MAXBUK];
  int t = threadIdx.x;
  for (int i = t; i < NB; i += 256) hist[i] = 0;
  __syncthreads();
  int e0 = blockIdx.x * PCHUNK;
  int e1 = min(e0 + PCHUNK, E);
  for (int i = e0 + t; i < e1; i += 256) atomicAdd(&hist[dst[i] >> GRP_SHIFT], 1);
  __syncthreads();
  for (int i = t; i < NB; i += 256)
    if (hist[i]) atomicAdd(&bcnt[i], hist[i]);
}

__global__ __launch_bounds__(256) void k_bucket_scan(const int* __restrict__ cnt,
                                                     int* __restrict__ base,
                                                     int* __restrict__ cur, int NB) {
  __shared__ int ts[256];
  int t = threadIdx.x;
  int v[4];
  int s = 0;
#pragma unroll
  for (int j = 0; j < 4; ++j) { int i = t * 4 + j; v[j] = (i < NB) ? cnt[i] : 0; s += v[j]; }
  ts[t] = s;
  __syncthreads();
  for (int o = 1; o < 256; o <<= 1) {
    int x = (t >= o) ? ts[t - o] : 0;
    __syncthreads();
    ts[t] += x;
    __syncthreads();
  }
  int run = ts[t] - s;
#pragma unroll
  for (int j = 0; j < 4; ++j) {
    int i = t * 4 + j;
    if (i < NB) { base[i] = run; cur[i] = run; }
    run += v[j];
  }
  if (t == 255) base[NB] = run;  // == E
}

__global__ __launch_bounds__(256) void k_partition(const int* __restrict__ src,
                                                   const int* __restrict__ dst,
                                                   int* __restrict__ bcur,
                                                   int2* __restrict__ pairs, int E, int NB) {
  __shared__ int hist[MAXBUK];
  __shared__ int base[MAXBUK];
  int t = threadIdx.x;
  for (int i = t; i < NB; i += 256) hist[i] = 0;
  __syncthreads();
  int e0 = blockIdx.x * PCHUNK;
  int e1 = min(e0 + PCHUNK, E);
  for (int i = e0 + t; i < e1; i += 256) atomicAdd(&hist[dst[i] >> GRP_SHIFT], 1);
  __syncthreads();
  for (int i = t; i < NB; i += 256) {
    int c = hist[i];
    base[i] = c ? atomicAdd(&bcur[i], c) : 0;
    hist[i] = 0;
  }
  __syncthreads();
  for (int i = e0 + t; i < e1; i += 256) {
    int d = dst[i];
    int b = d >> GRP_SHIFT;
    int r = atomicAdd(&hist[b], 1);
    pairs[base[b] + r] = make_int2(src[i], d);
  }
}

__global__ __launch_bounds__(256) void k_bucket_place(const int2* __restrict__ pairs,
                                                      const int* __restrict__ bbase,
                                                      int* __restrict__ offsets,
                                                      float* __restrict__ dinv,
                                                      int* __restrict__ csr, int N, int E) {
  __shared__ int cnt[128];
  __shared__ int sc[128];
  int t = threadIdx.x;
  int b = blockIdx.x;
  int node0 = b << GRP_SHIFT;
  if (t < 128) cnt[t] = 0;
  int beg = bbase[b], end = bbase[b + 1];
  if (b == 0 && t == 0) offsets[N] = E;
  __syncthreads();
  for (int i = beg + t; i < end; i += 256) atomicAdd(&cnt[pairs[i].y - node0], 1);
  __syncthreads();
  if (t < 128) sc[t] = cnt[t];
  __syncthreads();
  for (int o = 1; o < 128; o <<= 1) {
    int x = (t < 128 && t >= o) ? sc[t - o] : 0;
    __syncthreads();
    if (t < 128) sc[t] += x;
    __syncthreads();
  }
  if (t < 128) {
    int excl = sc[t] - cnt[t];
    int node = node0 + t;
    if (node < N) {
      offsets[node] = beg + excl;
      int d = cnt[t];
      dinv[node] = d > 0 ? rsqrtf((float)d) : 0.f;
    }
    sc[t] = beg + excl;  // becomes write cursor
  }
  __syncthreads();
  for (int i = beg + t; i < end; i += 256) {
    int2 e = pairs[i];
    int pos = atomicAdd(&sc[e.y - node0], 1);
    csr[pos] = e.x;
  }
}

// ---------- GEMM: out[m] = bf16( dinv[m] * (A[m] @ W) ), A:[M][K], W:[K][64] ----------
template <int K>
__global__ __launch_bounds__(256) void gemm_scale(const float* __restrict__ A,
                                                  const float* __restrict__ W,
                                                  const float* __restrict__ dinv,
                                                  unsigned short* __restrict__ out, int M) {
  __shared__ float xs[16][64];   // transposed A tile: xs[k][m]
  __shared__ float wsh[16][64];  // W tile: wsh[k][c]
  int t = threadIdx.x;
  int m0 = blockIdx.x * 64;
  int lm = t >> 2;
  int lk = (t & 3) << 2;
  int mr = (t & 15) << 2;
  int cc = (t >> 4) << 2;
  float acc[4][4] = {{0.f}};
  int gm = m0 + lm;
  const bool mok = gm < M;
  for (int kc = 0; kc < K; kc += 16) {
    float4 av = make_float4(0.f, 0.f, 0.f, 0.f);
    if (mok) av = *(const float4*)&A[(size_t)gm * K + kc + lk];
    float wv[4];
#pragma unroll
    for (int r = 0; r < 4; ++r) {
      int k = (t >> 6) + (r << 2);
      wv[r] = W[(size_t)(kc + k) * 64 + (t & 63)];
    }
    __syncthreads();
    xs[lk + 0][lm] = av.x;
    xs[lk + 1][lm] = av.y;
    xs[lk + 2][lm] = av.z;
    xs[lk + 3][lm] = av.w;
#pragma unroll
    for (int r = 0; r < 4; ++r) {
      int k = (t >> 6) + (r << 2);
      wsh[k][t & 63] = wv[r];
    }
    __syncthreads();
#pragma unroll
    for (int k = 0; k < 16; ++k) {
      float4 a4 = *(const float4*)&xs[k][mr];
      float4 b4 = *(const float4*)&wsh[k][cc];
      float a[4] = {a4.x, a4.y, a4.z, a4.w};
      float b[4] = {b4.x, b4.y, b4.z, b4.w};
#pragma unroll
      for (int i = 0; i < 4; ++i)
#pragma unroll
        for (int j = 0; j < 4; ++j) acc[i][j] = fmaf(a[i], b[j], acc[i][j]);
    }
  }
#pragma unroll
  for (int i = 0; i < 4; ++i) {
    int row = m0 + mr + i;
    if (row < M) {
      float sc = dinv[row];
      ushort4 o;
      o.x = f2bf(acc[i][0] * sc);
      o.y = f2bf(acc[i][1] * sc);
      o.z = f2bf(acc[i][2] * sc);
      o.w = f2bf(acc[i][3] * sc);
      *(ushort4*)&out[(size_t)row * 64 + cc] = o;
    }
  }
}

// ---------- aggregation + bias + LayerNorm + ReLU ----------
// wave per node; lane lh (0..31) owns feature pair {2lh, 2lh+1} (one uint = 2 bf16);
// the two 32-lane halves process two edges per load instruction (2x MLP).
__global__ __launch_bounds__(256) void k_agg(const unsigned* __restrict__ hs32,
                                             const int* __restrict__ offsets,
                                             const int* __restrict__ csr,
                                             const float* __restrict__ dinv,
                                             const float* __restrict__ b,
                                             const float* __restrict__ g,
                                             const float* __restrict__ tt,
                                             float* __restrict__ out, int n) {
  int lane = threadIdx.x & 63;
  int lh = lane & 31;
  int half = lane >> 5;
  int node = blockIdx.x * 4 + (threadIdx.x >> 6);
  if (node >= n) return;
  int beg = offsets[node];
  int end = offsets[node + 1];
  float aL = 0.f, aH = 0.f;
  int e = beg;
  for (; e + 16 <= end; e += 16) {   // 16 edges per iter: 8 loads, 2 edges each
#pragma unroll
    for (int j = 0; j < 8; ++j) {
      int s0 = csr[e + 2 * j];       // wave-uniform -> scalar loads
      int s1 = csr[e + 2 * j + 1];
      int sj = half ? s1 : s0;
      unsigned v = hs32[(size_t)sj * 32 + lh];
      aL += bfLo(v);
      aH += bfHi(v);
    }
  }
  for (; e + 2 <= end; e += 2) {
    int s0 = csr[e];
    int s1 = csr[e + 1];
    int sj = half ? s1 : s0;
    unsigned v = hs32[(size_t)sj * 32 + lh];
    aL += bfLo(v);
    aH += bfHi(v);
  }
  if (e < end && half == 0) {        // odd leftover edge: half 0 only
    unsigned v = hs32[(size_t)csr[e] * 32 + lh];
    aL += bfLo(v);
    aH += bfHi(v);
  }
  // combine the two halves' partial sums (after this both halves hold totals)
  aL += __shfl_xor(aL, 32, 64);
  aH += __shfl_xor(aH, 32, 64);
  float dv = dinv[node];
  float2 bb = *(const float2*)&b[lh * 2];
  float fL = fmaf(aL, dv, bb.x);
  float fH = fmaf(aH, dv, bb.y);
  float mu = wsum32(fL + fH) * 0.015625f;   // /64
  float dL = fL - mu, dH = fH - mu;
  float var = wsum32(dL * dL + dH * dH) * 0.015625f;
  float rs = rsqrtf(var + LN_EPS);
  float2 gg = *(const float2*)&g[lh * 2];
  float2 t2 = *(const float2*)&tt[lh * 2];
  float yL = fmaxf(fmaf(gg.x * dL, rs, t2.x), 0.f);
  float yH = fmaxf(fmaf(gg.y * dH, rs, t2.y), 0.f);
  if (half == 0) *(float2*)&out[(size_t)node * 64 + lh * 2] = make_float2(yL, yH);
}

// ---------- final: logits = h @ Wf + bf ; log_softmax ----------
// thread per node (2 nodes/thread): Wf reads are wave-uniform LDS broadcasts
// (5 ds_read_b128 per node vs 128 LDS ops in the shfl version).
__global__ __launch_bounds__(256) void k_final(const float* __restrict__ h,
                                               const float* __restrict__ Wf,
                                               const float* __restrict__ bf,
                                               float* __restrict__ out, int n) {
  __shared__ float Wl[64 * 40];
  __shared__ float bl[40];
  int t = threadIdx.x;
  for (int i = t; i < 64 * 40; i += 256) Wl[i] = Wf[i];
  if (t < 40) bl[t] = bf[t];
  __syncthreads();
  int n0 = blockIdx.x * 512 + t;
  int n1 = n0 + 256;
  const bool ok0 = n0 < n, ok1 = n1 < n;
  float acc0[40], acc1[40];
#pragma unroll
  for (int c = 0; c < 40; ++c) { acc0[c] = bl[c]; acc1[c] = bl[c]; }
  const float* h0 = &h[(size_t)n0 * 64];
  const float* h1 = &h[(size_t)n1 * 64];
#pragma unroll 2
  for (int k4 = 0; k4 < 16; ++k4) {
    float4 a4 = ok0 ? *(const float4*)&h0[k4 * 4] : make_float4(0.f, 0.f, 0.f, 0.f);
    float4 c4v = ok1 ? *(const float4*)&h1[k4 * 4] : make_float4(0.f, 0.f, 0.f, 0.f);
    float av[4] = {a4.x, a4.y, a4.z, a4.w};
    float bv[4] = {c4v.x, c4v.y, c4v.z, c4v.w};
#pragma unroll
    for (int j = 0; j < 4; ++j) {
      int k = k4 * 4 + j;
#pragma unroll
      for (int c4 = 0; c4 < 10; ++c4) {
        float4 w = *(const float4*)&Wl[k * 40 + c4 * 4];  // uniform -> broadcast
        acc0[c4 * 4 + 0] = fmaf(av[j], w.x, acc0[c4 * 4 + 0]);
        acc0[c4 * 4 + 1] = fmaf(av[j], w.y, acc0[c4 * 4 + 1]);
        acc0[c4 * 4 + 2] = fmaf(av[j], w.z, acc0[c4 * 4 + 2]);
        acc0[c4 * 4 + 3] = fmaf(av[j], w.w, acc0[c4 * 4 + 3]);
        acc1[c4 * 4 + 0] = fmaf(bv[j], w.x, acc1[c4 * 4 + 0]);
        acc1[c4 * 4 + 1] = fmaf(bv[j], w.y, acc1[c4 * 4 + 1]);
        acc1[c4 * 4 + 2] = fmaf(bv[j], w.z, acc1[c4 * 4 + 2]);
        acc1[c4 * 4 + 3] = fmaf(bv[j], w.w, acc1[c4 * 4 + 3]);
      }
    }
  }
  float m0 = acc0[0], m1 = acc1[0];
#pragma unroll
  for (int c = 1; c < 40; ++c) { m0 = fmaxf(m0, acc0[c]); m1 = fmaxf(m1, acc1[c]); }
  float s0 = 0.f, s1 = 0.f;
#pragma unroll
  for (int c = 0; c < 40; ++c) { s0 += expf(acc0[c] - m0); s1 += expf(acc1[c] - m1); }
  float l0 = m0 + logf(s0);
  float l1 = m1 + logf(s1);
#pragma unroll
  for (int c4 = 0; c4 < 10; ++c4) {
    if (ok0) {
      float4 o = make_float4(acc0[c4 * 4 + 0] - l0, acc0[c4 * 4 + 1] - l0,
                             acc0[c4 * 4 + 2] - l0, acc0[c4 * 4 + 3] - l0);
      *(float4*)&out[(size_t)n0 * 40 + c4 * 4] = o;
    }
    if (ok1) {
      float4 o = make_float4(acc1[c4 * 4 + 0] - l1, acc1[c4 * 4 + 1] - l1,
                             acc1[c4 * 4 + 2] - l1, acc1[c4 * 4 + 3] - l1);
      *(float4*)&out[(size_t)n1 * 40 + c4 * 4] = o;
    }
  }
}

// ---------- launch ----------
extern "C" void kernel_launch(void* const* d_in, const int* in_sizes, int n_in,
                              void* d_out, int out_size, void* d_ws, size_t ws_size,
                              hipStream_t stream) {
  const float* x  = (const float*)d_in[0];
  const int*   ei = (const int*)d_in[1];
  const float* W1 = (const float*)d_in[2];
  const float* b1 = (const float*)d_in[3];
  const float* g1 = (const float*)d_in[4];
  const float* t1 = (const float*)d_in[5];
  const float* W2 = (const float*)d_in[6];
  const float* b2 = (const float*)d_in[7];
  const float* g2 = (const float*)d_in[8];
  const float* t2 = (const float*)d_in[9];
  const float* W3 = (const float*)d_in[10];
  const float* b3 = (const float*)d_in[11];
  const float* g3 = (const float*)d_in[12];
  const float* t3 = (const float*)d_in[13];
  const float* Wf = (const float*)d_in[14];
  const float* bf = (const float*)d_in[15];
  float* out = (float*)d_out;

  const int N = in_sizes[0] / 128;
  const int E = in_sizes[1] / 2;
  const int* src = ei;
  const int* dst = ei + E;
  const int NBUK = (N + 127) >> GRP_SHIFT;
  const int NEB  = (E + PCHUNK - 1) / PCHUNK;

  char* p = (char*)d_ws;
  auto carve = [&](size_t bytes) -> char* {
    char* r = p;
    p += (bytes + 255) & ~(size_t)255;
    return r;
  };
  int*   bcnt    = (int*)carve((size_t)NBUK * 4);
  int*   bbase   = (int*)carve((size_t)(NBUK + 1) * 4);
  int*   bcur    = (int*)carve((size_t)NBUK * 4);
  int2*  pairs   = (int2*)carve((size_t)E * 8);
  int*   csr     = (int*)carve((size_t)E * 4);
  int*   offsets = (int*)carve((size_t)(N + 1) * 4);
  float* dinv    = (float*)carve((size_t)N * 4);
  unsigned short* hs = (unsigned short*)carve((size_t)N * 64 * 2);
  float* hA      = (float*)carve((size_t)N * 64 * 4);
  float* hB      = (float*)carve((size_t)N * 64 * 4);
  (void)ws_size; (void)n_in; (void)out_size;

  dim3 B(256);
  hipMemsetAsync(bcnt, 0, (size_t)NBUK * 4, stream);
  k_bucket_count<<<dim3(NEB), B, 0, stream>>>(dst, bcnt, E, NBUK);
  k_bucket_scan<<<dim3(1), B, 0, stream>>>(bcnt, bbase, bcur, NBUK);
  k_partition<<<dim3(NEB), B, 0, stream>>>(src, dst, bcur, pairs, E, NBUK);
  k_bucket_place<<<dim3(NBUK), B, 0, stream>>>(pairs, bbase, offsets, dinv, csr, N, E);

  const int GB = (N + 63) / 64;
  const int GA = (N + 3) / 4;
  const int GF = (N + 511) / 512;
  // layer 1
  gemm_scale<128><<<dim3(GB), B, 0, stream>>>(x, W1, dinv, hs, N);
  k_agg<<<dim3(GA), B, 0, stream>>>((const unsigned*)hs, offsets, csr, dinv, b1, g1, t1, hA, N);
  // layer 2
  gemm_scale<64><<<dim3(GB), B, 0, stream>>>(hA, W2, dinv, hs, N);
  k_agg<<<dim3(GA), B, 0, stream>>>((const unsigned*)hs, offsets, csr, dinv, b2, g2, t2, hB, N);
  // layer 3
  gemm_scale<64><<<dim3(GB), B, 0, stream>>>(hB, W3, dinv, hs, N);
  k_agg<<<dim3(GA), B, 0, stream>>>((const unsigned*)hs, offsets, csr, dinv, b3, g3, t3, hA, N);
  // final projection + log_softmax
  k_final<<<dim3(GF), B, 0, stream>>>(hA, Wf, bf, out, N);
}

// Round 6
// 289.400 us; speedup vs baseline: 2.1097x; 1.2638x over previous
//
#include <hip/hip_runtime.h>
#include <math.h>
#include <stdint.h>

#define LN_EPS 1e-5f
#define GRP_SHIFT 7           // 128 nodes per bucket
#define MAXBUK 1024           // N <= 131072
#define PCHUNK 8192           // edges per partition block

// ---------- bf16 helpers (RNE) ----------
__device__ __forceinline__ unsigned short f2bf(float f) {
  unsigned int u = __float_as_uint(f);
  unsigned int r = u + 0x7fffu + ((u >> 16) & 1u);
  return (unsigned short)(r >> 16);
}
__device__ __forceinline__ float bfLo(unsigned v) { return __uint_as_float(v << 16); }
__device__ __forceinline__ float bfHi(unsigned v) { return __uint_as_float(v & 0xffff0000u); }

// ---------- CSR build, bucketed counting sort ----------
__global__ __launch_bounds__(256) void k_bucket_count(const int* __restrict__ dst,
                                                      int* __restrict__ bcnt, int E, int NB) {
  __shared__ int hist[MAXBUK];
  int t = threadIdx.x;
  for (int i = t; i < NB; i += 256) hist[i] = 0;
  __syncthreads();
  int e0 = blockIdx.x * PCHUNK;
  int e1 = min(e0 + PCHUNK, E);
  for (int i = e0 + t; i < e1; i += 256) atomicAdd(&hist[dst[i] >> GRP_SHIFT], 1);
  __syncthreads();
  for (int i = t; i < NB; i += 256)
    if (hist[i]) atomicAdd(&bcnt[i], hist[i]);
}

__global__ __launch_bounds__(256) void k_bucket_scan(const int* __restrict__ cnt,
                                                     int* __restrict__ base,
                                                     int* __restrict__ cur, int NB) {
  __shared__ int ts[256];
  int t = threadIdx.x;
  int v[4];
  int s = 0;
#pragma unroll
  for (int j = 0; j < 4; ++j) { int i = t * 4 + j; v[j] = (i < NB) ? cnt[i] : 0; s += v[j]; }
  ts[t] = s;
  __syncthreads();
  for (int o = 1; o < 256; o <<= 1) {
    int x = (t >= o) ? ts[t - o] : 0;
    __syncthreads();
    ts[t] += x;
    __syncthreads();
  }
  int run = ts[t] - s;
#pragma unroll
  for (int j = 0; j < 4; ++j) {
    int i = t * 4 + j;
    if (i < NB) { base[i] = run; cur[i] = run; }
    run += v[j];
  }
  if (t == 255) base[NB] = run;  // == E
}

// partition edges into per-bucket regions; payload packed (src<<7)|dst_local (N < 2^25)
__global__ __launch_bounds__(256) void k_partition(const int* __restrict__ src,
                                                   const int* __restrict__ dst,
                                                   int* __restrict__ bcur,
                                                   unsigned* __restrict__ pairs, int E, int NB) {
  __shared__ int hist[MAXBUK];
  __shared__ int base[MAXBUK];
  int t = threadIdx.x;
  for (int i = t; i < NB; i += 256) hist[i] = 0;
  __syncthreads();
  int e0 = blockIdx.x * PCHUNK;
  int e1 = min(e0 + PCHUNK, E);
  for (int i = e0 + t; i < e1; i += 256) atomicAdd(&hist[dst[i] >> GRP_SHIFT], 1);
  __syncthreads();
  for (int i = t; i < NB; i += 256) {
    int c = hist[i];
    base[i] = c ? atomicAdd(&bcur[i], c) : 0;
    hist[i] = 0;
  }
  __syncthreads();
  for (int i = e0 + t; i < e1; i += 256) {
    int d = dst[i];
    int b = d >> GRP_SHIFT;
    int r = atomicAdd(&hist[b], 1);
    pairs[base[b] + r] = ((unsigned)src[i] << GRP_SHIFT) | (unsigned)(d & 127);
  }
}

__global__ __launch_bounds__(256) void k_bucket_place(const unsigned* __restrict__ pairs,
                                                      const int* __restrict__ bbase,
                                                      int* __restrict__ offsets,
                                                      float* __restrict__ dinv,
                                                      int* __restrict__ csr, int N, int E) {
  __shared__ int cnt[128];
  __shared__ int sc[128];
  int t = threadIdx.x;
  int b = blockIdx.x;
  int node0 = b << GRP_SHIFT;
  if (t < 128) cnt[t] = 0;
  int beg = bbase[b], end = bbase[b + 1];
  if (b == 0 && t == 0) offsets[N] = E;
  __syncthreads();
  for (int i = beg + t; i < end; i += 256) atomicAdd(&cnt[pairs[i] & 127u], 1);
  __syncthreads();
  if (t < 128) sc[t] = cnt[t];
  __syncthreads();
  for (int o = 1; o < 128; o <<= 1) {
    int x = (t < 128 && t >= o) ? sc[t - o] : 0;
    __syncthreads();
    if (t < 128) sc[t] += x;
    __syncthreads();
  }
  if (t < 128) {
    int excl = sc[t] - cnt[t];
    int node = node0 + t;
    if (node < N) {
      offsets[node] = beg + excl;
      int d = cnt[t];
      dinv[node] = d > 0 ? rsqrtf((float)d) : 0.f;
    }
    sc[t] = beg + excl;  // becomes write cursor
  }
  __syncthreads();
  for (int i = beg + t; i < end; i += 256) {
    unsigned pk = pairs[i];
    int pos = atomicAdd(&sc[pk & 127u], 1);
    csr[pos] = (int)(pk >> GRP_SHIFT);
  }
}

// ---------- GEMM: out[m] = bf16( dinv[m] * (A[m] @ W) ), A:[M][K], W:[K][64] ----------
template <int K>
__global__ __launch_bounds__(256) void gemm_scale(const float* __restrict__ A,
                                                  const float* __restrict__ W,
                                                  const float* __restrict__ dinv,
                                                  unsigned short* __restrict__ out, int M) {
  __shared__ float xs[16][64];   // transposed A tile: xs[k][m]
  __shared__ float wsh[16][64];  // W tile: wsh[k][c]
  int t = threadIdx.x;
  int m0 = blockIdx.x * 64;
  int lm = t >> 2;
  int lk = (t & 3) << 2;
  int mr = (t & 15) << 2;
  int cc = (t >> 4) << 2;
  float acc[4][4] = {{0.f}};
  int gm = m0 + lm;
  const bool mok = gm < M;
  for (int kc = 0; kc < K; kc += 16) {
    float4 av = make_float4(0.f, 0.f, 0.f, 0.f);
    if (mok) av = *(const float4*)&A[(size_t)gm * K + kc + lk];
    float wv[4];
#pragma unroll
    for (int r = 0; r < 4; ++r) {
      int k = (t >> 6) + (r << 2);
      wv[r] = W[(size_t)(kc + k) * 64 + (t & 63)];
    }
    __syncthreads();
    xs[lk + 0][lm] = av.x;
    xs[lk + 1][lm] = av.y;
    xs[lk + 2][lm] = av.z;
    xs[lk + 3][lm] = av.w;
#pragma unroll
    for (int r = 0; r < 4; ++r) {
      int k = (t >> 6) + (r << 2);
      wsh[k][t & 63] = wv[r];
    }
    __syncthreads();
#pragma unroll
    for (int k = 0; k < 16; ++k) {
      float4 a4 = *(const float4*)&xs[k][mr];
      float4 b4 = *(const float4*)&wsh[k][cc];
      float a[4] = {a4.x, a4.y, a4.z, a4.w};
      float b[4] = {b4.x, b4.y, b4.z, b4.w};
#pragma unroll
      for (int i = 0; i < 4; ++i)
#pragma unroll
        for (int j = 0; j < 4; ++j) acc[i][j] = fmaf(a[i], b[j], acc[i][j]);
    }
  }
#pragma unroll
  for (int i = 0; i < 4; ++i) {
    int row = m0 + mr + i;
    if (row < M) {
      float sc = dinv[row];
      ushort4 o;
      o.x = f2bf(acc[i][0] * sc);
      o.y = f2bf(acc[i][1] * sc);
      o.z = f2bf(acc[i][2] * sc);
      o.w = f2bf(acc[i][3] * sc);
      *(ushort4*)&out[(size_t)row * 64 + cc] = o;
    }
  }
}

// ---------- aggregation + bias + LayerNorm + ReLU ----------
// wave per node. lane = (q, fl): q = lane>>4 handles edge (e+4j+q); fl = lane&15 owns
// features 4fl..4fl+3 (uint2 = 8B = 4 bf16 per gather). 4 edges per wave-load, chunks of
// 16 edges fully unrolled + predicated (no serial tail); edge indices prefetched 64-wide.
__global__ __launch_bounds__(256) void k_agg(const uint2* __restrict__ hs64,
                                             const int* __restrict__ csr,
                                             const int* __restrict__ offsets,
                                             const float* __restrict__ dinv,
                                             const float* __restrict__ b,
                                             const float* __restrict__ g,
                                             const float* __restrict__ tt,
                                             float* __restrict__ out, int n) {
  int lane = threadIdx.x & 63;
  int q = lane >> 4;
  int fl = lane & 15;
  int node = blockIdx.x * 4 + (threadIdx.x >> 6);
  if (node >= n) return;
  int beg = offsets[node];
  int end = offsets[node + 1];
  float a0 = 0.f, a1 = 0.f, a2 = 0.f, a3 = 0.f;

#define GATH4(c)                                                        \
  {                                                                     \
    _Pragma("unroll") for (int j = 0; j < 4; ++j) {                     \
      int sj = __shfl(cs, 16 * (c) + 4 * j + q, 64);                    \
      uint2 v = hs64[(size_t)sj * 16 + fl];                             \
      float m = (e0 + 16 * (c) + 4 * j + q < end) ? 1.f : 0.f;          \
      a0 = fmaf(m, bfLo(v.x), a0);                                      \
      a1 = fmaf(m, bfHi(v.x), a1);                                      \
      a2 = fmaf(m, bfLo(v.y), a2);                                      \
      a3 = fmaf(m, bfHi(v.y), a3);                                      \
    }                                                                   \
  }

  for (int e0 = beg; e0 < end; e0 += 64) {
    int cs = csr[min(e0 + lane, end - 1)];  // 64 edge indices, one coalesced load
    GATH4(0);
    if (e0 + 16 < end) {
      GATH4(1);
      if (e0 + 32 < end) {
        GATH4(2);
        if (e0 + 48 < end) { GATH4(3); }
      }
    }
  }
#undef GATH4

  // combine the 4 quarters (after this every lane holds totals for its fl group)
  a0 += __shfl_xor(a0, 16, 64); a0 += __shfl_xor(a0, 32, 64);
  a1 += __shfl_xor(a1, 16, 64); a1 += __shfl_xor(a1, 32, 64);
  a2 += __shfl_xor(a2, 16, 64); a2 += __shfl_xor(a2, 32, 64);
  a3 += __shfl_xor(a3, 16, 64); a3 += __shfl_xor(a3, 32, 64);

  float dv = dinv[node];
  float4 bb = *(const float4*)&b[fl * 4];
  float v0 = fmaf(a0, dv, bb.x);
  float v1 = fmaf(a1, dv, bb.y);
  float v2 = fmaf(a2, dv, bb.z);
  float v3 = fmaf(a3, dv, bb.w);
  float s = v0 + v1 + v2 + v3;
#pragma unroll
  for (int m = 1; m < 16; m <<= 1) s += __shfl_xor(s, m, 64);
  float mu = s * 0.015625f;  // /64
  float d0 = v0 - mu, d1 = v1 - mu, d2 = v2 - mu, d3 = v3 - mu;
  float sv = d0 * d0 + d1 * d1 + d2 * d2 + d3 * d3;
#pragma unroll
  for (int m = 1; m < 16; m <<= 1) sv += __shfl_xor(sv, m, 64);
  float rs = rsqrtf(sv * 0.015625f + LN_EPS);
  float4 gg = *(const float4*)&g[fl * 4];
  float4 t4 = *(const float4*)&tt[fl * 4];
  if (q == 0) {
    float4 o;
    o.x = fmaxf(fmaf(gg.x * d0, rs, t4.x), 0.f);
    o.y = fmaxf(fmaf(gg.y * d1, rs, t4.y), 0.f);
    o.z = fmaxf(fmaf(gg.z * d2, rs, t4.z), 0.f);
    o.w = fmaxf(fmaf(gg.w * d3, rs, t4.w), 0.f);
    *(float4*)&out[(size_t)node * 64 + fl * 4] = o;
  }
}

// ---------- final: logits = h @ Wf + bf ; log_softmax (thread per node, 2 nodes/thread) ----------
__global__ __launch_bounds__(256) void k_final(const float* __restrict__ h,
                                               const float* __restrict__ Wf,
                                               const float* __restrict__ bf,
                                               float* __restrict__ out, int n) {
  __shared__ float Wl[64 * 40];
  __shared__ float bl[40];
  int t = threadIdx.x;
  for (int i = t; i < 64 * 40; i += 256) Wl[i] = Wf[i];
  if (t < 40) bl[t] = bf[t];
  __syncthreads();
  int n0 = blockIdx.x * 512 + t;
  int n1 = n0 + 256;
  const bool ok0 = n0 < n, ok1 = n1 < n;
  float acc0[40], acc1[40];
#pragma unroll
  for (int c = 0; c < 40; ++c) { acc0[c] = bl[c]; acc1[c] = bl[c]; }
  const float* h0 = &h[(size_t)n0 * 64];
  const float* h1 = &h[(size_t)n1 * 64];
#pragma unroll 2
  for (int k4 = 0; k4 < 16; ++k4) {
    float4 a4 = ok0 ? *(const float4*)&h0[k4 * 4] : make_float4(0.f, 0.f, 0.f, 0.f);
    float4 c4v = ok1 ? *(const float4*)&h1[k4 * 4] : make_float4(0.f, 0.f, 0.f, 0.f);
    float av[4] = {a4.x, a4.y, a4.z, a4.w};
    float bv[4] = {c4v.x, c4v.y, c4v.z, c4v.w};
#pragma unroll
    for (int j = 0; j < 4; ++j) {
      int k = k4 * 4 + j;
#pragma unroll
      for (int c4 = 0; c4 < 10; ++c4) {
        float4 w = *(const float4*)&Wl[k * 40 + c4 * 4];  // uniform -> broadcast
        acc0[c4 * 4 + 0] = fmaf(av[j], w.x, acc0[c4 * 4 + 0]);
        acc0[c4 * 4 + 1] = fmaf(av[j], w.y, acc0[c4 * 4 + 1]);
        acc0[c4 * 4 + 2] = fmaf(av[j], w.z, acc0[c4 * 4 + 2]);
        acc0[c4 * 4 + 3] = fmaf(av[j], w.w, acc0[c4 * 4 + 3]);
        acc1[c4 * 4 + 0] = fmaf(bv[j], w.x, acc1[c4 * 4 + 0]);
        acc1[c4 * 4 + 1] = fmaf(bv[j], w.y, acc1[c4 * 4 + 1]);
        acc1[c4 * 4 + 2] = fmaf(bv[j], w.z, acc1[c4 * 4 + 2]);
        acc1[c4 * 4 + 3] = fmaf(bv[j], w.w, acc1[c4 * 4 + 3]);
      }
    }
  }
  float m0 = acc0[0], m1 = acc1[0];
#pragma unroll
  for (int c = 1; c < 40; ++c) { m0 = fmaxf(m0, acc0[c]); m1 = fmaxf(m1, acc1[c]); }
  float s0 = 0.f, s1 = 0.f;
#pragma unroll
  for (int c = 0; c < 40; ++c) { s0 += expf(acc0[c] - m0); s1 += expf(acc1[c] - m1); }
  float l0 = m0 + logf(s0);
  float l1 = m1 + logf(s1);
#pragma unroll
  for (int c4 = 0; c4 < 10; ++c4) {
    if (ok0) {
      float4 o = make_float4(acc0[c4 * 4 + 0] - l0, acc0[c4 * 4 + 1] - l0,
                             acc0[c4 * 4 + 2] - l0, acc0[c4 * 4 + 3] - l0);
      *(float4*)&out[(size_t)n0 * 40 + c4 * 4] = o;
    }
    if (ok1) {
      float4 o = make_float4(acc1[c4 * 4 + 0] - l1, acc1[c4 * 4 + 1] - l1,
                             acc1[c4 * 4 + 2] - l1, acc1[c4 * 4 + 3] - l1);
      *(float4*)&out[(size_t)n1 * 40 + c4 * 4] = o;
    }
  }
}

// ---------- launch ----------
extern "C" void kernel_launch(void* const* d_in, const int* in_sizes, int n_in,
                              void* d_out, int out_size, void* d_ws, size_t ws_size,
                              hipStream_t stream) {
  const float* x  = (const float*)d_in[0];
  const int*   ei = (const int*)d_in[1];
  const float* W1 = (const float*)d_in[2];
  const float* b1 = (const float*)d_in[3];
  const float* g1 = (const float*)d_in[4];
  const float* t1 = (const float*)d_in[5];
  const float* W2 = (const float*)d_in[6];
  const float* b2 = (const float*)d_in[7];
  const float* g2 = (const float*)d_in[8];
  const float* t2 = (const float*)d_in[9];
  const float* W3 = (const float*)d_in[10];
  const float* b3 = (const float*)d_in[11];
  const float* g3 = (const float*)d_in[12];
  const float* t3 = (const float*)d_in[13];
  const float* Wf = (const float*)d_in[14];
  const float* bf = (const float*)d_in[15];
  float* out = (float*)d_out;

  const int N = in_sizes[0] / 128;
  const int E = in_sizes[1] / 2;
  const int* src = ei;
  const int* dst = ei + E;
  const int NBUK = (N + 127) >> GRP_SHIFT;
  const int NEB  = (E + PCHUNK - 1) / PCHUNK;

  char* p = (char*)d_ws;
  auto carve = [&](size_t bytes) -> char* {
    char* r = p;
    p += (bytes + 255) & ~(size_t)255;
    return r;
  };
  int*      bcnt    = (int*)carve((size_t)NBUK * 4);
  int*      bbase   = (int*)carve((size_t)(NBUK + 1) * 4);
  int*      bcur    = (int*)carve((size_t)NBUK * 4);
  unsigned* pairs   = (unsigned*)carve((size_t)E * 4);
  int*      csr     = (int*)carve((size_t)E * 4);
  int*      offsets = (int*)carve((size_t)(N + 1) * 4);
  float*    dinv    = (float*)carve((size_t)N * 4);
  unsigned short* hs = (unsigned short*)carve((size_t)N * 64 * 2);
  float*    hA      = (float*)carve((size_t)N * 64 * 4);
  float*    hB      = (float*)carve((size_t)N * 64 * 4);
  (void)ws_size; (void)n_in; (void)out_size;

  dim3 B(256);
  hipMemsetAsync(bcnt, 0, (size_t)NBUK * 4, stream);
  k_bucket_count<<<dim3(NEB), B, 0, stream>>>(dst, bcnt, E, NBUK);
  k_bucket_scan<<<dim3(1), B, 0, stream>>>(bcnt, bbase, bcur, NBUK);
  k_partition<<<dim3(NEB), B, 0, stream>>>(src, dst, bcur, pairs, E, NBUK);
  k_bucket_place<<<dim3(NBUK), B, 0, stream>>>(pairs, bbase, offsets, dinv, csr, N, E);

  const int GB = (N + 63) / 64;
  const int GA = (N + 3) / 4;
  const int GF = (N + 511) / 512;
  // layer 1
  gemm_scale<128><<<dim3(GB), B, 0, stream>>>(x, W1, dinv, hs, N);
  k_agg<<<dim3(GA), B, 0, stream>>>((const uint2*)hs, csr, offsets, dinv, b1, g1, t1, hA, N);
  // layer 2
  gemm_scale<64><<<dim3(GB), B, 0, stream>>>(hA, W2, dinv, hs, N);
  k_agg<<<dim3(GA), B, 0, stream>>>((const uint2*)hs, csr, offsets, dinv, b2, g2, t2, hB, N);
  // layer 3
  gemm_scale<64><<<dim3(GB), B, 0, stream>>>(hB, W3, dinv, hs, N);
  k_agg<<<dim3(GA), B, 0, stream>>>((const uint2*)hs, csr, offsets, dinv, b3, g3, t3, hA, N);
  // final projection + log_softmax
  k_final<<<dim3(GF), B, 0, stream>>>(hA, Wf, bf, out, N);
}